// Round 3
// baseline (1195.278 us; speedup 1.0000x reference)
//
#include <hip/hip_runtime.h>
#include <math.h>

#define I_DIM 384
#define C_DIM 128
#define H_NUM 4
#define HD_DIM 32
#define M_DIM (I_DIM*I_DIM)       // 147456
#define INF_F 1000000000.0f
#define EPS_F 1e-5f
#define QSCALE 0.17677669529663687f   // 1/sqrt(32)

__device__ __forceinline__ unsigned short f2bf(float f) {
    unsigned int u = __float_as_uint(f);
    u += 0x7fffu + ((u >> 16) & 1u);          // round-to-nearest-even
    return (unsigned short)(u >> 16);
}
__device__ __forceinline__ unsigned int pk2(float a, float b) {
    return (unsigned int)f2bf(a) | ((unsigned int)f2bf(b) << 16);
}
__device__ __forceinline__ float blo(unsigned int u){ return __uint_as_float(u << 16); }
__device__ __forceinline__ float bhi(unsigned int u){ return __uint_as_float(u & 0xffff0000u); }
__device__ __forceinline__ float s2f(unsigned short s){ return __uint_as_float(((unsigned int)s) << 16); }

// ---------------------------------------------------------------------------
// 8 rows x 4 cols micro-tile GEMM: acc = xs[rg*8..+7][:] @ w[:, cg..cg+3]
// ---------------------------------------------------------------------------
__device__ __forceinline__ void gemm_tile8x4(
    const float* __restrict__ w, const float* xs, int rg, int cg,
    float acc[8][4])
{
    #pragma unroll
    for (int rr = 0; rr < 8; rr++) {
        acc[rr][0] = 0.f; acc[rr][1] = 0.f; acc[rr][2] = 0.f; acc[rr][3] = 0.f;
    }
    #pragma unroll 2
    for (int kk = 0; kk < 128; kk += 4) {
        const float4 b0 = *(const float4*)&w[(size_t)(kk+0)*C_DIM + cg];
        const float4 b1 = *(const float4*)&w[(size_t)(kk+1)*C_DIM + cg];
        const float4 b2 = *(const float4*)&w[(size_t)(kk+2)*C_DIM + cg];
        const float4 b3 = *(const float4*)&w[(size_t)(kk+3)*C_DIM + cg];
        #pragma unroll
        for (int rr = 0; rr < 8; rr++) {
            const float4 a = *(const float4*)&xs[(rg*8+rr)*C_DIM + kk];
            acc[rr][0] += a.x*b0.x + a.y*b1.x + a.z*b2.x + a.w*b3.x;
            acc[rr][1] += a.x*b0.y + a.y*b1.y + a.z*b2.y + a.w*b3.y;
            acc[rr][2] += a.x*b0.z + a.y*b1.z + a.z*b2.z + a.w*b3.z;
            acc[rr][3] += a.x*b0.w + a.y*b1.w + a.z*b2.w + a.w*b3.w;
        }
    }
}

// ---------------------------------------------------------------------------
// Kernel 1: LayerNorm + z head + q/k/v/g projections.
// q fp32 (scaled), k/v bf16 (packed), g fp32 -> d_out, z fp32.
// ---------------------------------------------------------------------------
__global__ __launch_bounds__(256) void ln_proj_kernel(
    const float* __restrict__ x,
    const float* __restrict__ lnw, const float* __restrict__ lnb,
    const float* __restrict__ wq,  const float* __restrict__ wk,
    const float* __restrict__ wv,  const float* __restrict__ wg,
    const float* __restrict__ bg,  const float* __restrict__ wz,
    const float* __restrict__ bz,
    float* __restrict__ qo, unsigned short* __restrict__ ko16,
    unsigned short* __restrict__ vo16, float* __restrict__ go,
    float* __restrict__ zo)
{
    __shared__ __align__(16) float xs[64*C_DIM];   // 32 KB
    const int t    = threadIdx.x;
    const int row0 = blockIdx.x * 64;

    // ---- Phase A: LayerNorm (4 lanes per row, 32 channels each) ----
    {
        const int r = t >> 2, qt = t & 3, c0 = qt * 32;
        const float* xrow = x + (size_t)(row0 + r)*C_DIM + c0;
        float4 xv[8];
        float s = 0.f, ss = 0.f;
        #pragma unroll
        for (int i2 = 0; i2 < 8; i2++) {
            xv[i2] = ((const float4*)xrow)[i2];
            s  += xv[i2].x + xv[i2].y + xv[i2].z + xv[i2].w;
            ss += xv[i2].x*xv[i2].x + xv[i2].y*xv[i2].y
                + xv[i2].z*xv[i2].z + xv[i2].w*xv[i2].w;
        }
        s  += __shfl_xor(s, 1);  s  += __shfl_xor(s, 2);
        ss += __shfl_xor(ss, 1); ss += __shfl_xor(ss, 2);
        const float mean = s * (1.f/128.f);
        const float var  = ss * (1.f/128.f) - mean*mean;
        const float rstd = rsqrtf(var + EPS_F);
        #pragma unroll
        for (int i2 = 0; i2 < 8; i2++) {
            float4 w4 = ((const float4*)(lnw + c0))[i2];
            float4 b4 = ((const float4*)(lnb + c0))[i2];
            float4 r4;
            r4.x = (xv[i2].x - mean)*rstd*w4.x + b4.x;
            r4.y = (xv[i2].y - mean)*rstd*w4.y + b4.y;
            r4.z = (xv[i2].z - mean)*rstd*w4.z + b4.z;
            r4.w = (xv[i2].w - mean)*rstd*w4.w + b4.w;
            *(float4*)&xs[r*C_DIM + c0 + i2*4] = r4;
        }
    }
    __syncthreads();

    // ---- Phase B: z head (x_ln @ wz + bz), one (row,h) per thread ----
    {
        const int zr = t >> 2, zh = t & 3;
        float acc = bz[zh];
        const float4* xr4 = (const float4*)&xs[zr*C_DIM];
        #pragma unroll 8
        for (int k4 = 0; k4 < 32; k4++) {
            float4 a = xr4[k4];
            const float* wzp = wz + k4*16 + zh;
            acc += a.x*wzp[0] + a.y*wzp[4] + a.z*wzp[8] + a.w*wzp[12];
        }
        zo[(size_t)zh*M_DIM + row0 + zr] = acc;
    }

    // ---- Phase C: 4 projections, 8 rows x 4 cols per thread ----
    const int rg = t >> 5;
    const int cg = (t & 31) * 4;
    float acc[8][4];

    // q (scaled)
    gemm_tile8x4(wq, xs, rg, cg, acc);
    #pragma unroll
    for (int rr = 0; rr < 8; rr++) {
        const size_t row = (size_t)(row0 + rg*8 + rr);
        float4 r4 = make_float4(acc[rr][0]*QSCALE, acc[rr][1]*QSCALE,
                                acc[rr][2]*QSCALE, acc[rr][3]*QSCALE);
        *(float4*)&qo[row*C_DIM + cg] = r4;
    }
    // k (bf16)
    gemm_tile8x4(wk, xs, rg, cg, acc);
    #pragma unroll
    for (int rr = 0; rr < 8; rr++) {
        const size_t row = (size_t)(row0 + rg*8 + rr);
        uint2 pw;
        pw.x = pk2(acc[rr][0], acc[rr][1]);
        pw.y = pk2(acc[rr][2], acc[rr][3]);
        *(uint2*)&ko16[row*C_DIM + cg] = pw;
    }
    // v (bf16)
    gemm_tile8x4(wv, xs, rg, cg, acc);
    #pragma unroll
    for (int rr = 0; rr < 8; rr++) {
        const size_t row = (size_t)(row0 + rg*8 + rr);
        uint2 pw;
        pw.x = pk2(acc[rr][0], acc[rr][1]);
        pw.y = pk2(acc[rr][2], acc[rr][3]);
        *(uint2*)&vo16[row*C_DIM + cg] = pw;
    }
    // g (sigmoid)
    gemm_tile8x4(wg, xs, rg, cg, acc);
    const float4 bg4 = *(const float4*)&bg[cg];
    #pragma unroll
    for (int rr = 0; rr < 8; rr++) {
        const size_t row = (size_t)(row0 + rg*8 + rr);
        float4 r4;
        r4.x = 1.f/(1.f+__expf(-(acc[rr][0]+bg4.x)));
        r4.y = 1.f/(1.f+__expf(-(acc[rr][1]+bg4.y)));
        r4.z = 1.f/(1.f+__expf(-(acc[rr][2]+bg4.z)));
        r4.w = 1.f/(1.f+__expf(-(acc[rr][3]+bg4.w)));
        *(float4*)&go[row*C_DIM + cg] = r4;
    }
}

// ---------------------------------------------------------------------------
// Kernel 2: attention. One block per (i,h). K,V bf16 in LDS, channel-group-
// major [8 groups of 4ch][384 keys], padded row (386) to spread banks.
// exp-scores ps in bf16; ALL ps accesses are unsigned short (TBAA-safe).
// q and o alias (same buffer, disjoint rows per wave) -> NO __restrict__.
// Static LDS = 24704*2 + 12288 + 1536 = 63232 B (< 64 KB).
// ---------------------------------------------------------------------------
__global__ __launch_bounds__(256) void attn_kernel(
    const float* q, const unsigned short* __restrict__ k16,
    const unsigned short* __restrict__ v16, const float* __restrict__ zb,
    const float* __restrict__ mask, float* o)
{
    __shared__ uint2 Kl[8][386];
    __shared__ uint2 Vl[8][386];
    __shared__ unsigned short ps[4][4][384];
    __shared__ float mb[384];

    const int h  = blockIdx.x;
    const int ii = blockIdx.y;
    const int t  = threadIdx.x;
    const size_t rbase = (size_t)ii*384*C_DIM + h*HD_DIM;  // element offset

    // ---- stage K, V ----
    for (int idx = t; idx < 384*4; idx += 256) {
        const int j = idx >> 2, c8 = idx & 3;
        const uint4 kv = *(const uint4*)&k16[rbase + (size_t)j*C_DIM + c8*8];
        const uint4 vv = *(const uint4*)&v16[rbase + (size_t)j*C_DIM + c8*8];
        Kl[2*c8  ][j] = make_uint2(kv.x, kv.y);
        Kl[2*c8+1][j] = make_uint2(kv.z, kv.w);
        Vl[2*c8  ][j] = make_uint2(vv.x, vv.y);
        Vl[2*c8+1][j] = make_uint2(vv.z, vv.w);
    }
    for (int jj = t; jj < 384; jj += 256)
        mb[jj] = INF_F * (mask[(size_t)ii*384 + jj] - 1.f);
    __syncthreads();

    const int w = t >> 6, l = t & 63;
    const float* zrow = zb + (size_t)h*M_DIM;
    const int cgP = l & 7, ksP = l >> 3;       // PV lane mapping

    float mbr[6];
    #pragma unroll
    for (int j6 = 0; j6 < 6; j6++) mbr[j6] = mb[l + 64*j6];

    #pragma unroll 1
    for (int qb = 0; qb < 96; qb += 4) {
        const int q0 = w*96 + qb;

        // ---- scores: lane l owns keys {l, l+64, ..., l+320} ----
        float sc[4][6];
        #pragma unroll
        for (int qi = 0; qi < 4; qi++)
            #pragma unroll
            for (int j6 = 0; j6 < 6; j6++)
                sc[qi][j6] = mbr[j6] + zrow[(size_t)(q0+qi)*I_DIM + l + 64*j6];

        #pragma unroll 2
        for (int cg = 0; cg < 8; cg++) {
            const float4 qv0 = *(const float4*)&q[rbase + (size_t)(q0+0)*C_DIM + cg*4];
            const float4 qv1 = *(const float4*)&q[rbase + (size_t)(q0+1)*C_DIM + cg*4];
            const float4 qv2 = *(const float4*)&q[rbase + (size_t)(q0+2)*C_DIM + cg*4];
            const float4 qv3 = *(const float4*)&q[rbase + (size_t)(q0+3)*C_DIM + cg*4];
            #pragma unroll
            for (int j6 = 0; j6 < 6; j6++) {
                const int kk = l + 64*j6;
                const uint2 u = Kl[cg][kk];
                const float k0 = blo(u.x), k1 = bhi(u.x);
                const float k2 = blo(u.y), k3 = bhi(u.y);
                sc[0][j6] += qv0.x*k0 + qv0.y*k1 + qv0.z*k2 + qv0.w*k3;
                sc[1][j6] += qv1.x*k0 + qv1.y*k1 + qv1.z*k2 + qv1.w*k3;
                sc[2][j6] += qv2.x*k0 + qv2.y*k1 + qv2.z*k2 + qv2.w*k3;
                sc[3][j6] += qv3.x*k0 + qv3.y*k1 + qv3.z*k2 + qv3.w*k3;
            }
        }

        // ---- softmax (unnormalized exp -> ps bf16, keep 1/sum in regs) ----
        float rcp[4];
        #pragma unroll
        for (int qi = 0; qi < 4; qi++) {
            float mx = sc[qi][0];
            #pragma unroll
            for (int j6 = 1; j6 < 6; j6++) mx = fmaxf(mx, sc[qi][j6]);
            #pragma unroll
            for (int off = 32; off >= 1; off >>= 1) mx = fmaxf(mx, __shfl_xor(mx, off));
            float sum = 0.f;
            #pragma unroll
            for (int j6 = 0; j6 < 6; j6++) {
                const float e = __expf(sc[qi][j6] - mx);
                sum += e;
                ps[w][qi][l + 64*j6] = f2bf(e);
            }
            #pragma unroll
            for (int off = 32; off >= 1; off >>= 1) sum += __shfl_xor(sum, off);
            rcp[qi] = 1.f / sum;
        }

        // ---- PV: lane = (channel-group cgP, key-slice ksP of 48 keys) ----
        float acc[4][4];
        #pragma unroll
        for (int qi = 0; qi < 4; qi++) {
            acc[qi][0]=0.f; acc[qi][1]=0.f; acc[qi][2]=0.f; acc[qi][3]=0.f;
        }
        const int kBase = ksP * 48;
        #pragma unroll 4
        for (int kp = 0; kp < 24; kp++) {
            const int kk = kBase + 2*kp;
            const uint2 va  = Vl[cgP][kk];
            const uint2 vb2 = Vl[cgP][kk+1];
            const float v00=blo(va.x),  v01=bhi(va.x),  v02=blo(va.y),  v03=bhi(va.y);
            const float v10=blo(vb2.x), v11=bhi(vb2.x), v12=blo(vb2.y), v13=bhi(vb2.y);
            #pragma unroll
            for (int qi = 0; qi < 4; qi++) {
                const float p0 = s2f(ps[w][qi][kk]);     // short loads only:
                const float p1 = s2f(ps[w][qi][kk+1]);   // TBAA-consistent with writes
                acc[qi][0] += p0*v00 + p1*v10;
                acc[qi][1] += p0*v01 + p1*v11;
                acc[qi][2] += p0*v02 + p1*v12;
                acc[qi][3] += p0*v03 + p1*v13;
            }
        }
        // reduce over the 8 key-slices (lane bits 3..5)
        #pragma unroll
        for (int off = 8; off <= 32; off <<= 1)
            #pragma unroll
            for (int qi = 0; qi < 4; qi++) {
                acc[qi][0] += __shfl_xor(acc[qi][0], off);
                acc[qi][1] += __shfl_xor(acc[qi][1], off);
                acc[qi][2] += __shfl_xor(acc[qi][2], off);
                acc[qi][3] += __shfl_xor(acc[qi][3], off);
            }
        if (l < 8) {
            #pragma unroll
            for (int qi = 0; qi < 4; qi++) {
                float4 r4 = make_float4(acc[qi][0]*rcp[qi], acc[qi][1]*rcp[qi],
                                        acc[qi][2]*rcp[qi], acc[qi][3]*rcp[qi]);
                *(float4*)&o[rbase + (size_t)(q0+qi)*C_DIM + cgP*4] = r4;
            }
        }
    }
}

// ---------------------------------------------------------------------------
// Kernel 3: out = (o * g) @ wo + bo. g lives in d_out; overwritten in place
// (block-local read-before-write) -> g/out NOT __restrict__.
// ---------------------------------------------------------------------------
__global__ __launch_bounds__(256) void out_proj_kernel(
    const float* __restrict__ o, const float* g,
    const float* __restrict__ wo, const float* __restrict__ bo,
    float* out)
{
    __shared__ __align__(16) float xs[64*C_DIM];
    const int t    = threadIdx.x;
    const int row0 = blockIdx.x * 64;
    {
        const int r = t >> 2, c0 = (t & 3)*32;
        const float4* orow = (const float4*)(o + (size_t)(row0+r)*C_DIM + c0);
        const float4* grow = (const float4*)(g + (size_t)(row0+r)*C_DIM + c0);
        #pragma unroll
        for (int i2 = 0; i2 < 8; i2++) {
            float4 a = orow[i2];
            const float4 b = grow[i2];
            a.x *= b.x; a.y *= b.y; a.z *= b.z; a.w *= b.w;
            *(float4*)&xs[r*C_DIM + c0 + i2*4] = a;
        }
    }
    __syncthreads();

    const int rg = t >> 5, cg = (t & 31)*4;
    float acc[8][4];
    gemm_tile8x4(wo, xs, rg, cg, acc);
    const float4 b4 = *(const float4*)&bo[cg];
    #pragma unroll
    for (int rr = 0; rr < 8; rr++) {
        float4 r4 = make_float4(acc[rr][0]+b4.x, acc[rr][1]+b4.y,
                                acc[rr][2]+b4.z, acc[rr][3]+b4.w);
        *(float4*)&out[(size_t)(row0 + rg*8 + rr)*C_DIM + cg] = r4;
    }
}

extern "C" void kernel_launch(void* const* d_in, const int* in_sizes, int n_in,
                              void* d_out, int out_size, void* d_ws, size_t ws_size,
                              hipStream_t stream)
{
    (void)in_sizes; (void)n_in; (void)out_size; (void)ws_size;
    const float* x    = (const float*)d_in[0];
    const float* mask = (const float*)d_in[1];
    const float* lnw  = (const float*)d_in[2];
    const float* lnb  = (const float*)d_in[3];
    const float* wz   = (const float*)d_in[4];
    const float* bz   = (const float*)d_in[5];
    const float* wq   = (const float*)d_in[6];
    const float* wk   = (const float*)d_in[7];
    const float* wv   = (const float*)d_in[8];
    const float* wg   = (const float*)d_in[9];
    const float* bg   = (const float*)d_in[10];
    const float* wo   = (const float*)d_in[11];
    const float* bo   = (const float*)d_in[12];

    // ws layout (153.4 MB total):
    //   qb   fp32 M*128  (q; o written over it by attention, disjoint rows/ch)
    //   zbuf fp32 4*M
    //   kb16 bf16 M*128
    //   vb16 bf16 M*128
    float* ws = (float*)d_ws;
    float* qb   = ws;
    float* zbuf = qb + (size_t)M_DIM*C_DIM;
    unsigned short* kb16 = (unsigned short*)(zbuf + (size_t)H_NUM*M_DIM);
    unsigned short* vb16 = kb16 + (size_t)M_DIM*C_DIM;
    float* gbuf = (float*)d_out;     // g parked in d_out, consumed by kernel 3

    ln_proj_kernel<<<M_DIM/64, 256, 0, stream>>>(
        x, lnw, lnb, wq, wk, wv, wg, bg, wz, bz, qb, kb16, vb16, gbuf, zbuf);
    attn_kernel<<<dim3(H_NUM, I_DIM), 256, 0, stream>>>(
        qb, kb16, vb16, zbuf, mask, qb /* o over q */);
    out_proj_kernel<<<M_DIM/64, 256, 0, stream>>>(
        qb, gbuf, wo, bo, (float*)d_out);
}

// Round 4
// 1062.597 us; speedup vs baseline: 1.1249x; 1.1249x over previous
//
#include <hip/hip_runtime.h>
#include <math.h>

#define I_DIM 384
#define C_DIM 128
#define H_NUM 4
#define HD_DIM 32
#define M_DIM (I_DIM*I_DIM)       // 147456
#define INF_F 1000000000.0f
#define EPS_F 1e-5f
#define QSCALE 0.17677669529663687f   // 1/sqrt(32)

typedef __attribute__((ext_vector_type(8))) short short8;
typedef __attribute__((ext_vector_type(4))) float f32x4;
union U4S8 { uint4 u; short8 s; };

__device__ __forceinline__ unsigned short f2bf(float f) {
    unsigned int u = __float_as_uint(f);
    u += 0x7fffu + ((u >> 16) & 1u);          // round-to-nearest-even
    return (unsigned short)(u >> 16);
}
__device__ __forceinline__ unsigned int pk2(float a, float b) {
    return (unsigned int)f2bf(a) | ((unsigned int)f2bf(b) << 16);
}

// ---------------------------------------------------------------------------
// 8 rows x 4 cols micro-tile GEMM: acc = xs[rg*8..+7][:] @ w[:, cg..cg+3]
// ---------------------------------------------------------------------------
__device__ __forceinline__ void gemm_tile8x4(
    const float* __restrict__ w, const float* xs, int rg, int cg,
    float acc[8][4])
{
    #pragma unroll
    for (int rr = 0; rr < 8; rr++) {
        acc[rr][0] = 0.f; acc[rr][1] = 0.f; acc[rr][2] = 0.f; acc[rr][3] = 0.f;
    }
    #pragma unroll 2
    for (int kk = 0; kk < 128; kk += 4) {
        const float4 b0 = *(const float4*)&w[(size_t)(kk+0)*C_DIM + cg];
        const float4 b1 = *(const float4*)&w[(size_t)(kk+1)*C_DIM + cg];
        const float4 b2 = *(const float4*)&w[(size_t)(kk+2)*C_DIM + cg];
        const float4 b3 = *(const float4*)&w[(size_t)(kk+3)*C_DIM + cg];
        #pragma unroll
        for (int rr = 0; rr < 8; rr++) {
            const float4 a = *(const float4*)&xs[(rg*8+rr)*C_DIM + kk];
            acc[rr][0] += a.x*b0.x + a.y*b1.x + a.z*b2.x + a.w*b3.x;
            acc[rr][1] += a.x*b0.y + a.y*b1.y + a.z*b2.y + a.w*b3.y;
            acc[rr][2] += a.x*b0.z + a.y*b1.z + a.z*b2.z + a.w*b3.z;
            acc[rr][3] += a.x*b0.w + a.y*b1.w + a.z*b2.w + a.w*b3.w;
        }
    }
}

// ---------------------------------------------------------------------------
// Kernel 1: LayerNorm + z head + q/k/v/g projections.
// q fp32 (scaled), k bf16 row-major, v bf16 TRANSPOSED ([i][c][j] uint pairs),
// g fp32 -> d_out, z fp32.
// ---------------------------------------------------------------------------
__global__ __launch_bounds__(256) void ln_proj_kernel(
    const float* __restrict__ x,
    const float* __restrict__ lnw, const float* __restrict__ lnb,
    const float* __restrict__ wq,  const float* __restrict__ wk,
    const float* __restrict__ wv,  const float* __restrict__ wg,
    const float* __restrict__ bg,  const float* __restrict__ wz,
    const float* __restrict__ bz,
    float* __restrict__ qo, unsigned short* __restrict__ ko16,
    unsigned int* __restrict__ vto, float* __restrict__ go,
    float* __restrict__ zo)
{
    __shared__ __align__(16) float xs[64*C_DIM];   // 32 KB
    const int t    = threadIdx.x;
    const int row0 = blockIdx.x * 64;

    // ---- Phase A: LayerNorm (4 lanes per row, 32 channels each) ----
    {
        const int r = t >> 2, qt = t & 3, c0 = qt * 32;
        const float* xrow = x + (size_t)(row0 + r)*C_DIM + c0;
        float4 xv[8];
        float s = 0.f, ss = 0.f;
        #pragma unroll
        for (int i2 = 0; i2 < 8; i2++) {
            xv[i2] = ((const float4*)xrow)[i2];
            s  += xv[i2].x + xv[i2].y + xv[i2].z + xv[i2].w;
            ss += xv[i2].x*xv[i2].x + xv[i2].y*xv[i2].y
                + xv[i2].z*xv[i2].z + xv[i2].w*xv[i2].w;
        }
        s  += __shfl_xor(s, 1);  s  += __shfl_xor(s, 2);
        ss += __shfl_xor(ss, 1); ss += __shfl_xor(ss, 2);
        const float mean = s * (1.f/128.f);
        const float var  = ss * (1.f/128.f) - mean*mean;
        const float rstd = rsqrtf(var + EPS_F);
        #pragma unroll
        for (int i2 = 0; i2 < 8; i2++) {
            float4 w4 = ((const float4*)(lnw + c0))[i2];
            float4 b4 = ((const float4*)(lnb + c0))[i2];
            float4 r4;
            r4.x = (xv[i2].x - mean)*rstd*w4.x + b4.x;
            r4.y = (xv[i2].y - mean)*rstd*w4.y + b4.y;
            r4.z = (xv[i2].z - mean)*rstd*w4.z + b4.z;
            r4.w = (xv[i2].w - mean)*rstd*w4.w + b4.w;
            *(float4*)&xs[r*C_DIM + c0 + i2*4] = r4;
        }
    }
    __syncthreads();

    // ---- Phase B: z head (x_ln @ wz + bz), one (row,h) per thread ----
    {
        const int zr = t >> 2, zh = t & 3;
        float acc = bz[zh];
        const float4* xr4 = (const float4*)&xs[zr*C_DIM];
        #pragma unroll 8
        for (int k4 = 0; k4 < 32; k4++) {
            float4 a = xr4[k4];
            const float* wzp = wz + k4*16 + zh;
            acc += a.x*wzp[0] + a.y*wzp[4] + a.z*wzp[8] + a.w*wzp[12];
        }
        zo[(size_t)zh*M_DIM + row0 + zr] = acc;
    }

    // ---- Phase C: 4 projections, 8 rows x 4 cols per thread ----
    const int rg = t >> 5;
    const int cg = (t & 31) * 4;
    float acc[8][4];

    // q (scaled, fp32)
    gemm_tile8x4(wq, xs, rg, cg, acc);
    #pragma unroll
    for (int rr = 0; rr < 8; rr++) {
        const size_t row = (size_t)(row0 + rg*8 + rr);
        float4 r4 = make_float4(acc[rr][0]*QSCALE, acc[rr][1]*QSCALE,
                                acc[rr][2]*QSCALE, acc[rr][3]*QSCALE);
        *(float4*)&qo[row*C_DIM + cg] = r4;
    }
    // k (bf16 row-major)
    gemm_tile8x4(wk, xs, rg, cg, acc);
    #pragma unroll
    for (int rr = 0; rr < 8; rr++) {
        const size_t row = (size_t)(row0 + rg*8 + rr);
        uint2 pw;
        pw.x = pk2(acc[rr][0], acc[rr][1]);
        pw.y = pk2(acc[rr][2], acc[rr][3]);
        *(uint2*)&ko16[row*C_DIM + cg] = pw;
    }
    // v (bf16 transposed: vto[(i*128 + c)*192 + j/2], uint = {j even, j odd})
    gemm_tile8x4(wv, xs, rg, cg, acc);
    {
        const int i_blk = row0 / I_DIM;            // 64-row block lies in one i
        const int jbase = (row0 % I_DIM) + rg*8;
        #pragma unroll
        for (int cc = 0; cc < 4; cc++)
            #pragma unroll
            for (int p = 0; p < 4; p++) {
                unsigned int u = pk2(acc[2*p][cc], acc[2*p+1][cc]);
                vto[((size_t)i_blk*C_DIM + cg + cc)*192 + (jbase>>1) + p] = u;
            }
    }
    // g (sigmoid, fp32 -> d_out)
    gemm_tile8x4(wg, xs, rg, cg, acc);
    const float4 bg4 = *(const float4*)&bg[cg];
    #pragma unroll
    for (int rr = 0; rr < 8; rr++) {
        const size_t row = (size_t)(row0 + rg*8 + rr);
        float4 r4;
        r4.x = 1.f/(1.f+__expf(-(acc[rr][0]+bg4.x)));
        r4.y = 1.f/(1.f+__expf(-(acc[rr][1]+bg4.y)));
        r4.z = 1.f/(1.f+__expf(-(acc[rr][2]+bg4.z)));
        r4.w = 1.f/(1.f+__expf(-(acc[rr][3]+bg4.w)));
        *(float4*)&go[row*C_DIM + cg] = r4;
    }
}

// ---------------------------------------------------------------------------
// Kernel 2: MFMA attention. One block per (i,h); 4 waves, wave w owns queries
// [w*96, w*96+96). S tiles via mfma_f32_16x16x32_bf16 (A=Q rows, B=K rows),
// softmax in C-layout, P transposed to A-layout through per-wave uint LDS in
// 96-key chunks, PV with B-frags from pre-transposed V. LDS 63744 B, 2 blk/CU.
// ---------------------------------------------------------------------------
__global__ __launch_bounds__(256, 2) void attn_mfma_kernel(
    const float* q, const unsigned short* __restrict__ k16,
    const unsigned int* __restrict__ vt32, const float* __restrict__ zb,
    const float* __restrict__ mask, float* o)
{
    __shared__ uint4 Ks4[384*4];          // K rows bf16: 24576 B
    __shared__ uint4 VTl[32*49];          // V^T rows bf16, stride 49: 25088 B
    __shared__ unsigned int PbU[4*784];   // per-wave P chunk, stride 49: 12544 B
    __shared__ float mbl[384];            // 1536 B

    const int h  = blockIdx.x;
    const int ii = blockIdx.y;
    const int t  = threadIdx.x;
    const size_t rbase = (size_t)ii*I_DIM*C_DIM + h*HD_DIM;

    // ---- stage K (row-major) and V^T ----
    for (int idx = t; idx < 1536; idx += 256) {
        const int j = idx >> 2, c4 = idx & 3;
        Ks4[j*4 + c4] = ((const uint4*)k16)[rbase/8 + (size_t)j*16 + c4];
    }
    for (int idx = t; idx < 1536; idx += 256) {
        const int d = idx / 48, m = idx - d*48;
        VTl[d*49 + m] = ((const uint4*)vt32)[((size_t)ii*C_DIM + h*HD_DIM + d)*48 + m];
    }
    for (int jj = t; jj < 384; jj += 256)
        mbl[jj] = INF_F * (mask[(size_t)ii*I_DIM + jj] - 1.f);
    __syncthreads();

    const int w = t >> 6, l = t & 63;
    const int n16 = l & 15, quad = l >> 4;

    float mbr[24];
    #pragma unroll
    for (int kt = 0; kt < 24; kt++) mbr[kt] = mbl[kt*16 + n16];

    #pragma unroll 1
    for (int qt = 0; qt < 6; qt++) {
        const int qg = w*6 + qt;          // q-tile index; rows qg*16..+15

        // ---- A-frag: Q rows fp32 -> bf16 ----
        U4S8 a;
        {
            const float* qrow = q + rbase + (size_t)(qg*16 + n16)*C_DIM + quad*8;
            const float4 f0 = ((const float4*)qrow)[0];
            const float4 f1 = ((const float4*)qrow)[1];
            a.u = make_uint4(pk2(f0.x,f0.y), pk2(f0.z,f0.w),
                             pk2(f1.x,f1.y), pk2(f1.z,f1.w));
        }

        // ---- QK^T: 24 mfma ----
        f32x4 accS[24];
        #pragma unroll
        for (int kt = 0; kt < 24; kt++) {
            U4S8 b;
            b.u = Ks4[(kt*16 + n16)*4 + quad];
            accS[kt] = __builtin_amdgcn_mfma_f32_16x16x32_bf16(
                a.s, b.s, (f32x4){0.f,0.f,0.f,0.f}, 0, 0, 0);
        }

        // ---- bias + softmax (C-layout: row q = quad*4+r, col k = kt*16+n16) ----
        float rcp4[4];
        #pragma unroll
        for (int r = 0; r < 4; r++) {
            const float* zq = zb + (size_t)h*M_DIM
                            + (size_t)(qg*16 + quad*4 + r)*I_DIM + n16;
            float zv[24];
            #pragma unroll
            for (int kt = 0; kt < 24; kt++) zv[kt] = zq[kt*16];
            float m_ = -INF_F;
            #pragma unroll
            for (int kt = 0; kt < 24; kt++) {
                const float s = accS[kt][r] + mbr[kt] + zv[kt];
                accS[kt][r] = s;
                m_ = fmaxf(m_, s);
            }
            m_ = fmaxf(m_, __shfl_xor(m_, 1));
            m_ = fmaxf(m_, __shfl_xor(m_, 2));
            m_ = fmaxf(m_, __shfl_xor(m_, 4));
            m_ = fmaxf(m_, __shfl_xor(m_, 8));
            float ss = 0.f;
            #pragma unroll
            for (int kt = 0; kt < 24; kt++) {
                const float e = __expf(accS[kt][r] - m_);
                accS[kt][r] = e;
                ss += e;
            }
            ss += __shfl_xor(ss, 1);
            ss += __shfl_xor(ss, 2);
            ss += __shfl_xor(ss, 4);
            ss += __shfl_xor(ss, 8);
            rcp4[r] = 1.f / ss;
        }

        // ---- PV in 96-key chunks through per-wave LDS transpose ----
        f32x4 oacc0 = {0.f,0.f,0.f,0.f}, oacc1 = {0.f,0.f,0.f,0.f};
        #pragma unroll 1
        for (int c = 0; c < 4; c++) {
            // write chunk (pair adjacent keys via shfl, even lanes store uint)
            #pragma unroll
            for (int k6 = 0; k6 < 6; k6++) {
                const int kt = 6*c + k6;
                #pragma unroll
                for (int r = 0; r < 4; r++) {
                    const float e  = accS[kt][r];
                    const float eo = __shfl_xor(e, 1);
                    if (!(l & 1))
                        PbU[w*784 + (quad*4+r)*49 + k6*8 + (n16 >> 1)] = pk2(e, eo);
                }
            }
            // read back as A-frags, mfma against V^T B-frags
            #pragma unroll
            for (int km = 0; km < 3; km++) {
                const int pbase = w*784 + n16*49 + quad*4 + 16*km;
                U4S8 pa;
                pa.u = make_uint4(PbU[pbase], PbU[pbase+1], PbU[pbase+2], PbU[pbase+3]);
                U4S8 vb0, vb1;
                vb0.u = VTl[(n16     )*49 + quad + 4*km + 12*c];
                vb1.u = VTl[(16 + n16)*49 + quad + 4*km + 12*c];
                oacc0 = __builtin_amdgcn_mfma_f32_16x16x32_bf16(pa.s, vb0.s, oacc0, 0,0,0);
                oacc1 = __builtin_amdgcn_mfma_f32_16x16x32_bf16(pa.s, vb1.s, oacc1, 0,0,0);
            }
        }

        // ---- store O (C-layout) ----
        #pragma unroll
        for (int r = 0; r < 4; r++) {
            const size_t orow = rbase + (size_t)(qg*16 + quad*4 + r)*C_DIM;
            o[orow + n16]      = oacc0[r] * rcp4[r];
            o[orow + 16 + n16] = oacc1[r] * rcp4[r];
        }
    }
}

// ---------------------------------------------------------------------------
// Kernel 3: out = (o * g) @ wo + bo. g lives in d_out; overwritten in place.
// ---------------------------------------------------------------------------
__global__ __launch_bounds__(256) void out_proj_kernel(
    const float* __restrict__ o, const float* g,
    const float* __restrict__ wo, const float* __restrict__ bo,
    float* out)
{
    __shared__ __align__(16) float xs[64*C_DIM];
    const int t    = threadIdx.x;
    const int row0 = blockIdx.x * 64;
    {
        const int r = t >> 2, c0 = (t & 3)*32;
        const float4* orow = (const float4*)(o + (size_t)(row0+r)*C_DIM + c0);
        const float4* grow = (const float4*)(g + (size_t)(row0+r)*C_DIM + c0);
        #pragma unroll
        for (int i2 = 0; i2 < 8; i2++) {
            float4 a = orow[i2];
            const float4 b = grow[i2];
            a.x *= b.x; a.y *= b.y; a.z *= b.z; a.w *= b.w;
            *(float4*)&xs[r*C_DIM + c0 + i2*4] = a;
        }
    }
    __syncthreads();

    const int rg = t >> 5, cg = (t & 31)*4;
    float acc[8][4];
    gemm_tile8x4(wo, xs, rg, cg, acc);
    const float4 b4 = *(const float4*)&bo[cg];
    #pragma unroll
    for (int rr = 0; rr < 8; rr++) {
        float4 r4 = make_float4(acc[rr][0]+b4.x, acc[rr][1]+b4.y,
                                acc[rr][2]+b4.z, acc[rr][3]+b4.w);
        *(float4*)&out[(size_t)(row0 + rg*8 + rr)*C_DIM + cg] = r4;
    }
}

extern "C" void kernel_launch(void* const* d_in, const int* in_sizes, int n_in,
                              void* d_out, int out_size, void* d_ws, size_t ws_size,
                              hipStream_t stream)
{
    (void)in_sizes; (void)n_in; (void)out_size; (void)ws_size;
    const float* x    = (const float*)d_in[0];
    const float* mask = (const float*)d_in[1];
    const float* lnw  = (const float*)d_in[2];
    const float* lnb  = (const float*)d_in[3];
    const float* wz   = (const float*)d_in[4];
    const float* bz   = (const float*)d_in[5];
    const float* wq   = (const float*)d_in[6];
    const float* wk   = (const float*)d_in[7];
    const float* wv   = (const float*)d_in[8];
    const float* wg   = (const float*)d_in[9];
    const float* bg   = (const float*)d_in[10];
    const float* wo   = (const float*)d_in[11];
    const float* bo   = (const float*)d_in[12];

    // ws layout (153.4 MB):
    //   qb   fp32 M*128  (q; o overwrites it in attention)
    //   zbuf fp32 4*M
    //   kb16 bf16 M*128 row-major
    //   vt32 bf16 M*128 transposed [i][c][j], packed uint pairs along j
    float* ws = (float*)d_ws;
    float* qb   = ws;
    float* zbuf = qb + (size_t)M_DIM*C_DIM;
    unsigned short* kb16 = (unsigned short*)(zbuf + (size_t)H_NUM*M_DIM);
    unsigned int*   vt32 = (unsigned int*)(kb16 + (size_t)M_DIM*C_DIM);
    float* gbuf = (float*)d_out;     // g parked in d_out, consumed by kernel 3

    ln_proj_kernel<<<M_DIM/64, 256, 0, stream>>>(
        x, lnw, lnb, wq, wk, wv, wg, bg, wz, bz, qb, kb16, vt32, gbuf, zbuf);
    attn_mfma_kernel<<<dim3(H_NUM, I_DIM), 256, 0, stream>>>(
        qb, kb16, vt32, zbuf, mask, qb /* o over q */);
    out_proj_kernel<<<M_DIM/64, 256, 0, stream>>>(
        qb, gbuf, wo, bo, (float*)d_out);
}

// Round 5
// 742.770 us; speedup vs baseline: 1.6092x; 1.4306x over previous
//
#include <hip/hip_runtime.h>
#include <math.h>

#define I_DIM 384
#define C_DIM 128
#define H_NUM 4
#define HD_DIM 32
#define M_DIM (I_DIM*I_DIM)       // 147456
#define INF_F 1000000000.0f
#define EPS_F 1e-5f
#define QSCALE 0.17677669529663687f   // 1/sqrt(32)

typedef __attribute__((ext_vector_type(8))) short short8;
typedef __attribute__((ext_vector_type(4))) float f32x4;
union U4S8 { uint4 u; short8 s; };

__device__ __forceinline__ unsigned short f2bf(float f) {
    unsigned int u = __float_as_uint(f);
    u += 0x7fffu + ((u >> 16) & 1u);          // round-to-nearest-even
    return (unsigned short)(u >> 16);
}
__device__ __forceinline__ unsigned int pk2(float a, float b) {
    return (unsigned int)f2bf(a) | ((unsigned int)f2bf(b) << 16);
}

// ---------------------------------------------------------------------------
// 8 rows x 4 cols micro-tile GEMM: acc = xs[rg*8..+7][:] @ w[:, cg..cg+3]
// ---------------------------------------------------------------------------
__device__ __forceinline__ void gemm_tile8x4(
    const float* __restrict__ w, const float* xs, int rg, int cg,
    float acc[8][4])
{
    #pragma unroll
    for (int rr = 0; rr < 8; rr++) {
        acc[rr][0] = 0.f; acc[rr][1] = 0.f; acc[rr][2] = 0.f; acc[rr][3] = 0.f;
    }
    #pragma unroll 2
    for (int kk = 0; kk < 128; kk += 4) {
        const float4 b0 = *(const float4*)&w[(size_t)(kk+0)*C_DIM + cg];
        const float4 b1 = *(const float4*)&w[(size_t)(kk+1)*C_DIM + cg];
        const float4 b2 = *(const float4*)&w[(size_t)(kk+2)*C_DIM + cg];
        const float4 b3 = *(const float4*)&w[(size_t)(kk+3)*C_DIM + cg];
        #pragma unroll
        for (int rr = 0; rr < 8; rr++) {
            const float4 a = *(const float4*)&xs[(rg*8+rr)*C_DIM + kk];
            acc[rr][0] += a.x*b0.x + a.y*b1.x + a.z*b2.x + a.w*b3.x;
            acc[rr][1] += a.x*b0.y + a.y*b1.y + a.z*b2.y + a.w*b3.y;
            acc[rr][2] += a.x*b0.z + a.y*b1.z + a.z*b2.z + a.w*b3.z;
            acc[rr][3] += a.x*b0.w + a.y*b1.w + a.z*b2.w + a.w*b3.w;
        }
    }
}

// ---------------------------------------------------------------------------
// Kernel 1: LayerNorm + z head + q/k/v/g projections.
// q fp32 (scaled), k bf16 row-major, v bf16 TRANSPOSED via LDS (coalesced),
// g fp32 -> d_out, z fp32.
// ---------------------------------------------------------------------------
__global__ __launch_bounds__(256) void ln_proj_kernel(
    const float* __restrict__ x,
    const float* __restrict__ lnw, const float* __restrict__ lnb,
    const float* __restrict__ wq,  const float* __restrict__ wk,
    const float* __restrict__ wv,  const float* __restrict__ wg,
    const float* __restrict__ bg,  const float* __restrict__ wz,
    const float* __restrict__ bz,
    float* __restrict__ qo, unsigned short* __restrict__ ko16,
    unsigned int* __restrict__ vto, float* __restrict__ go,
    float* __restrict__ zo)
{
    __shared__ __align__(16) float xs[64*C_DIM];     // 32 KB
    __shared__ unsigned int vts[128*33];             // 16.9 KB transpose buf
    const int t    = threadIdx.x;
    const int row0 = blockIdx.x * 64;

    // ---- Phase A: LayerNorm (4 lanes per row, 32 channels each) ----
    {
        const int r = t >> 2, qt = t & 3, c0 = qt * 32;
        const float* xrow = x + (size_t)(row0 + r)*C_DIM + c0;
        float4 xv[8];
        float s = 0.f, ss = 0.f;
        #pragma unroll
        for (int i2 = 0; i2 < 8; i2++) {
            xv[i2] = ((const float4*)xrow)[i2];
            s  += xv[i2].x + xv[i2].y + xv[i2].z + xv[i2].w;
            ss += xv[i2].x*xv[i2].x + xv[i2].y*xv[i2].y
                + xv[i2].z*xv[i2].z + xv[i2].w*xv[i2].w;
        }
        s  += __shfl_xor(s, 1);  s  += __shfl_xor(s, 2);
        ss += __shfl_xor(ss, 1); ss += __shfl_xor(ss, 2);
        const float mean = s * (1.f/128.f);
        const float var  = ss * (1.f/128.f) - mean*mean;
        const float rstd = rsqrtf(var + EPS_F);
        #pragma unroll
        for (int i2 = 0; i2 < 8; i2++) {
            float4 w4 = ((const float4*)(lnw + c0))[i2];
            float4 b4 = ((const float4*)(lnb + c0))[i2];
            float4 r4;
            r4.x = (xv[i2].x - mean)*rstd*w4.x + b4.x;
            r4.y = (xv[i2].y - mean)*rstd*w4.y + b4.y;
            r4.z = (xv[i2].z - mean)*rstd*w4.z + b4.z;
            r4.w = (xv[i2].w - mean)*rstd*w4.w + b4.w;
            *(float4*)&xs[r*C_DIM + c0 + i2*4] = r4;
        }
    }
    __syncthreads();

    // ---- Phase B: z head (x_ln @ wz + bz), one (row,h) per thread ----
    {
        const int zr = t >> 2, zh = t & 3;
        float acc = bz[zh];
        const float4* xr4 = (const float4*)&xs[zr*C_DIM];
        #pragma unroll 8
        for (int k4 = 0; k4 < 32; k4++) {
            float4 a = xr4[k4];
            const float* wzp = wz + k4*16 + zh;
            acc += a.x*wzp[0] + a.y*wzp[4] + a.z*wzp[8] + a.w*wzp[12];
        }
        zo[(size_t)zh*M_DIM + row0 + zr] = acc;
    }

    // ---- Phase C: 4 projections, 8 rows x 4 cols per thread ----
    const int rg = t >> 5;
    const int cg = (t & 31) * 4;
    float acc[8][4];

    // q (scaled, fp32)
    gemm_tile8x4(wq, xs, rg, cg, acc);
    #pragma unroll
    for (int rr = 0; rr < 8; rr++) {
        const size_t row = (size_t)(row0 + rg*8 + rr);
        float4 r4 = make_float4(acc[rr][0]*QSCALE, acc[rr][1]*QSCALE,
                                acc[rr][2]*QSCALE, acc[rr][3]*QSCALE);
        *(float4*)&qo[row*C_DIM + cg] = r4;
    }
    // k (bf16 row-major)
    gemm_tile8x4(wk, xs, rg, cg, acc);
    #pragma unroll
    for (int rr = 0; rr < 8; rr++) {
        const size_t row = (size_t)(row0 + rg*8 + rr);
        uint2 pw;
        pw.x = pk2(acc[rr][0], acc[rr][1]);
        pw.y = pk2(acc[rr][2], acc[rr][3]);
        *(uint2*)&ko16[row*C_DIM + cg] = pw;
    }
    // v -> LDS transpose -> coalesced global store
    // vto[(i*128 + c)*192 + j/2], uint = {j even, j odd}
    gemm_tile8x4(wv, xs, rg, cg, acc);
    #pragma unroll
    for (int cc = 0; cc < 4; cc++)
        #pragma unroll
        for (int p = 0; p < 4; p++)
            vts[(cg+cc)*33 + rg*4 + p] = pk2(acc[2*p][cc], acc[2*p+1][cc]);
    __syncthreads();
    {
        const int i_blk = row0 / I_DIM;            // 64-row block lies in one i
        const int jp0   = (row0 % I_DIM) >> 1;
        for (int idx = t; idx < 128*32; idx += 256) {
            const int ch = idx >> 5, p = idx & 31;
            vto[((size_t)i_blk*C_DIM + ch)*192 + jp0 + p] = vts[ch*33 + p];
        }
    }
    // g (sigmoid, fp32 -> d_out)
    gemm_tile8x4(wg, xs, rg, cg, acc);
    const float4 bg4 = *(const float4*)&bg[cg];
    #pragma unroll
    for (int rr = 0; rr < 8; rr++) {
        const size_t row = (size_t)(row0 + rg*8 + rr);
        float4 r4;
        r4.x = 1.f/(1.f+__expf(-(acc[rr][0]+bg4.x)));
        r4.y = 1.f/(1.f+__expf(-(acc[rr][1]+bg4.y)));
        r4.z = 1.f/(1.f+__expf(-(acc[rr][2]+bg4.z)));
        r4.w = 1.f/(1.f+__expf(-(acc[rr][3]+bg4.w)));
        *(float4*)&go[row*C_DIM + cg] = r4;
    }
}

// ---------------------------------------------------------------------------
// Kernel 2: MFMA attention, chunked (online, no-max softmax: exp(s)/sum —
// mathematically identical; scores are O(1), mask bias only goes to -1e9).
// One block per (ii,h), grid = (I, H) so same-h blocks cluster -> z L2-hits.
// Per 96-key chunk: 6 QK mfma -> bias+exp (accS[6] only: ~85 VGPR, no spill)
// -> P chunk to per-wave LDS -> 6 PV mfma. LDS 63.7 KB, 2 blocks/CU.
// ---------------------------------------------------------------------------
__global__ __launch_bounds__(256, 2) void attn_mfma_kernel(
    const float* q, const unsigned short* __restrict__ k16,
    const unsigned int* __restrict__ vt32, const float* __restrict__ zb,
    const float* __restrict__ mask, float* o)
{
    __shared__ uint4 Ks4[384*4];          // K rows bf16: 24576 B
    __shared__ uint4 VTl[32*49];          // V^T rows bf16, stride 49: 25088 B
    __shared__ unsigned int PbU[4*784];   // per-wave P chunk, stride 49: 12544 B
    __shared__ float mbl[384];            // 1536 B

    const int ii = blockIdx.x;
    const int h  = blockIdx.y;
    const int t  = threadIdx.x;
    const size_t rbase = (size_t)ii*I_DIM*C_DIM + h*HD_DIM;

    // ---- stage K (row-major head slice) and V^T ----
    for (int idx = t; idx < 1536; idx += 256) {
        const int j = idx >> 2, c4 = idx & 3;
        Ks4[j*4 + c4] = ((const uint4*)k16)[rbase/8 + (size_t)j*16 + c4];
    }
    for (int idx = t; idx < 1536; idx += 256) {
        const int d = idx / 48, m = idx - d*48;
        VTl[d*49 + m] = ((const uint4*)vt32)[((size_t)ii*C_DIM + h*HD_DIM + d)*48 + m];
    }
    for (int jj = t; jj < 384; jj += 256)
        mbl[jj] = INF_F * (mask[(size_t)ii*I_DIM + jj] - 1.f);
    __syncthreads();

    const int w = t >> 6, l = t & 63;
    const int n16 = l & 15, quad = l >> 4;

    #pragma unroll 1
    for (int qt = 0; qt < 6; qt++) {
        const int qg = w*6 + qt;          // q-tile index; rows qg*16..+15

        // ---- A-frag: Q rows fp32 -> bf16 ----
        U4S8 a;
        {
            const float* qrow = q + rbase + (size_t)(qg*16 + n16)*C_DIM + quad*8;
            const float4 f0 = ((const float4*)qrow)[0];
            const float4 f1 = ((const float4*)qrow)[1];
            a.u = make_uint4(pk2(f0.x,f0.y), pk2(f0.z,f0.w),
                             pk2(f1.x,f1.y), pk2(f1.z,f1.w));
        }

        f32x4 oacc0 = {0.f,0.f,0.f,0.f}, oacc1 = {0.f,0.f,0.f,0.f};
        float lsum[4] = {0.f, 0.f, 0.f, 0.f};
        const float* zbase = zb + (size_t)h*M_DIM
                           + (size_t)(qg*16 + quad*4)*I_DIM + n16;

        #pragma unroll 1
        for (int c = 0; c < 4; c++) {
            // z bias for this chunk (issued early; QK mfma hides latency)
            float zc[4][6];
            #pragma unroll
            for (int r = 0; r < 4; r++)
                #pragma unroll
                for (int k6 = 0; k6 < 6; k6++)
                    zc[r][k6] = zbase[(size_t)r*I_DIM + (6*c + k6)*16];
            float mbc[6];
            #pragma unroll
            for (int k6 = 0; k6 < 6; k6++)
                mbc[k6] = mbl[(6*c + k6)*16 + n16];

            // ---- QK^T: 6 mfma ----
            f32x4 accS[6];
            #pragma unroll
            for (int k6 = 0; k6 < 6; k6++) {
                U4S8 b;
                b.u = Ks4[((6*c + k6)*16 + n16)*4 + quad];
                accS[k6] = __builtin_amdgcn_mfma_f32_16x16x32_bf16(
                    a.s, b.s, (f32x4){0.f,0.f,0.f,0.f}, 0, 0, 0);
            }

            // ---- bias + exp (no max-sub) + partial row sums ----
            #pragma unroll
            for (int r = 0; r < 4; r++)
                #pragma unroll
                for (int k6 = 0; k6 < 6; k6++) {
                    const float e = __expf(accS[k6][r] + mbc[k6] + zc[r][k6]);
                    accS[k6][r] = e;
                    lsum[r] += e;
                }

            // ---- P chunk -> per-wave LDS (pair adjacent keys via shfl) ----
            #pragma unroll
            for (int k6 = 0; k6 < 6; k6++)
                #pragma unroll
                for (int r = 0; r < 4; r++) {
                    const float e  = accS[k6][r];
                    const float eo = __shfl_xor(e, 1);
                    if (!(l & 1))
                        PbU[w*784 + (quad*4+r)*49 + k6*8 + (n16 >> 1)] = pk2(e, eo);
                }

            // ---- PV: 3 km x 2 halves ----
            #pragma unroll
            for (int km = 0; km < 3; km++) {
                const int pbase = w*784 + n16*49 + quad*4 + 16*km;
                U4S8 pa;
                pa.u = make_uint4(PbU[pbase], PbU[pbase+1], PbU[pbase+2], PbU[pbase+3]);
                U4S8 vb0, vb1;
                vb0.u = VTl[(n16     )*49 + quad + 4*km + 12*c];
                vb1.u = VTl[(16 + n16)*49 + quad + 4*km + 12*c];
                oacc0 = __builtin_amdgcn_mfma_f32_16x16x32_bf16(pa.s, vb0.s, oacc0, 0,0,0);
                oacc1 = __builtin_amdgcn_mfma_f32_16x16x32_bf16(pa.s, vb1.s, oacc1, 0,0,0);
            }
        }

        // ---- normalize + store O (C-layout) ----
        #pragma unroll
        for (int r = 0; r < 4; r++) {
            float s_ = lsum[r];
            s_ += __shfl_xor(s_, 1);
            s_ += __shfl_xor(s_, 2);
            s_ += __shfl_xor(s_, 4);
            s_ += __shfl_xor(s_, 8);
            const float rcp = 1.f / s_;
            const size_t orow = rbase + (size_t)(qg*16 + quad*4 + r)*C_DIM;
            o[orow + n16]      = oacc0[r] * rcp;
            o[orow + 16 + n16] = oacc1[r] * rcp;
        }
    }
}

// ---------------------------------------------------------------------------
// Kernel 3: out = (o * g) @ wo + bo. g lives in d_out; overwritten in place.
// ---------------------------------------------------------------------------
__global__ __launch_bounds__(256) void out_proj_kernel(
    const float* __restrict__ o, const float* g,
    const float* __restrict__ wo, const float* __restrict__ bo,
    float* out)
{
    __shared__ __align__(16) float xs[64*C_DIM];
    const int t    = threadIdx.x;
    const int row0 = blockIdx.x * 64;
    {
        const int r = t >> 2, c0 = (t & 3)*32;
        const float4* orow = (const float4*)(o + (size_t)(row0+r)*C_DIM + c0);
        const float4* grow = (const float4*)(g + (size_t)(row0+r)*C_DIM + c0);
        #pragma unroll
        for (int i2 = 0; i2 < 8; i2++) {
            float4 a = orow[i2];
            const float4 b = grow[i2];
            a.x *= b.x; a.y *= b.y; a.z *= b.z; a.w *= b.w;
            *(float4*)&xs[r*C_DIM + c0 + i2*4] = a;
        }
    }
    __syncthreads();

    const int rg = t >> 5, cg = (t & 31)*4;
    float acc[8][4];
    gemm_tile8x4(wo, xs, rg, cg, acc);
    const float4 b4 = *(const float4*)&bo[cg];
    #pragma unroll
    for (int rr = 0; rr < 8; rr++) {
        float4 r4 = make_float4(acc[rr][0]+b4.x, acc[rr][1]+b4.y,
                                acc[rr][2]+b4.z, acc[rr][3]+b4.w);
        *(float4*)&out[(size_t)(row0 + rg*8 + rr)*C_DIM + cg] = r4;
    }
}

extern "C" void kernel_launch(void* const* d_in, const int* in_sizes, int n_in,
                              void* d_out, int out_size, void* d_ws, size_t ws_size,
                              hipStream_t stream)
{
    (void)in_sizes; (void)n_in; (void)out_size; (void)ws_size;
    const float* x    = (const float*)d_in[0];
    const float* mask = (const float*)d_in[1];
    const float* lnw  = (const float*)d_in[2];
    const float* lnb  = (const float*)d_in[3];
    const float* wz   = (const float*)d_in[4];
    const float* bz   = (const float*)d_in[5];
    const float* wq   = (const float*)d_in[6];
    const float* wk   = (const float*)d_in[7];
    const float* wv   = (const float*)d_in[8];
    const float* wg   = (const float*)d_in[9];
    const float* bg   = (const float*)d_in[10];
    const float* wo   = (const float*)d_in[11];
    const float* bo   = (const float*)d_in[12];

    // ws layout (153.4 MB):
    //   qb   fp32 M*128  (q; o overwrites it in attention)
    //   zbuf fp32 4*M
    //   kb16 bf16 M*128 row-major
    //   vt32 bf16 M*128 transposed [i][c][j], packed uint pairs along j
    float* ws = (float*)d_ws;
    float* qb   = ws;
    float* zbuf = qb + (size_t)M_DIM*C_DIM;
    unsigned short* kb16 = (unsigned short*)(zbuf + (size_t)H_NUM*M_DIM);
    unsigned int*   vt32 = (unsigned int*)(kb16 + (size_t)M_DIM*C_DIM);
    float* gbuf = (float*)d_out;     // g parked in d_out, consumed by kernel 3

    ln_proj_kernel<<<M_DIM/64, 256, 0, stream>>>(
        x, lnw, lnb, wq, wk, wv, wg, bg, wz, bz, qb, kb16, vt32, gbuf, zbuf);
    attn_mfma_kernel<<<dim3(I_DIM, H_NUM), 256, 0, stream>>>(
        qb, kb16, vt32, zbuf, mask, qb /* o over q */);
    out_proj_kernel<<<M_DIM/64, 256, 0, stream>>>(
        qb, gbuf, wo, bo, (float*)d_out);
}